// Round 9
// baseline (3635.766 us; speedup 1.0000x reference)
//
#include <hip/hip_runtime.h>
#include <math.h>

#define T 128
#define B 128
#define H 256
#define I 256
#define G4 1024  // 4*H
#define NB 2     // batch elements per block

typedef unsigned short u16;
typedef unsigned int u32;
typedef _Float16 half_t;
typedef _Float16 half2_t __attribute__((ext_vector_type(2)));

#if defined(__has_builtin)
#if __has_builtin(__builtin_amdgcn_fdot2)
#define HAS_FDOT2 1
#endif
#endif

__device__ __forceinline__ float fdot2(half2_t a, half2_t b, float c) {
#ifdef HAS_FDOT2
    return __builtin_amdgcn_fdot2(a, b, c, false);
#else
    return fmaf((float)a.x, (float)b.x, fmaf((float)a.y, (float)b.y, c));
#endif
}
__device__ __forceinline__ half2_t h2cast(u32 u) { return __builtin_bit_cast(half2_t, u); }

__device__ __forceinline__ float sigmoid_fast(float x) {
    return 1.0f / (1.0f + __expf(-x));
}
__device__ __forceinline__ float tanh_fast(float x) {
    x = fminf(fmaxf(x, -15.f), 15.f);
    const float e = __expf(2.0f * x);
    return (e - 1.0f) / (e + 1.0f);
}

// Raw barrier: drain LDS only (lgkmcnt), do NOT drain vmcnt — register-destined
// global prefetches stay in flight across phases. asm "memory" clobbers fence
// compiler-level reordering; sched_barrier(0) pins the schedule.
#define BAR() do {                                                  \
    asm volatile("s_waitcnt lgkmcnt(0)" ::: "memory");              \
    __builtin_amdgcn_s_barrier();                                   \
    asm volatile("" ::: "memory");                                  \
    __builtin_amdgcn_sched_barrier(0);                              \
} while (0)

// ---------------- weight repack (one-shot, fp16 o-major / row-contiguous) ----------------
// WhO[o][k2] = half2{Whh[o][2k2], Whh[o][2k2+1]} : row = 128 half2 = 512 B contiguous
__global__ void pack_whO(const float* __restrict__ Whh, half2_t* __restrict__ WhO) {
    const int o  = blockIdx.x;      // 0..1023
    const int k2 = threadIdx.x;     // 0..127
    half2_t v;
    v.x = (half_t)Whh[(size_t)o * H + 2 * k2];
    v.y = (half_t)Whh[(size_t)o * H + 2 * k2 + 1];
    WhO[(size_t)o * 128 + k2] = v;
}
// WaO[j][k2] = half2{Wa[j][2k2], Wa[j][2k2+1]} : row = 256 half2 = 1 KB contiguous
__global__ void pack_waO(const float* __restrict__ Wa, half2_t* __restrict__ WaO) {
    const int j  = blockIdx.x;      // 0..255
    const int k2 = threadIdx.x;     // 0..255
    half2_t v;
    v.x = (half_t)Wa[(size_t)j * (2 * H) + 2 * k2];
    v.y = (half_t)Wa[(size_t)j * (2 * H) + 2 * k2 + 1];
    WaO[(size_t)j * 256 + k2] = v;
}

// ---------------- G = embs @ Wih^T + bih + bhh ----------------
__global__ __launch_bounds__(256) void gemm_g(const float* __restrict__ A,
                                              const float* __restrict__ W,
                                              const float* __restrict__ bih,
                                              const float* __restrict__ bhh,
                                              float* __restrict__ G) {
    __shared__ __align__(16) float As[64][68];
    __shared__ __align__(16) float Ws[64][68];
    const int m0 = blockIdx.x * 64;
    const int n0 = blockIdx.y * 64;
    const int tid = threadIdx.x;
    const int ty = tid >> 4, tx = tid & 15;
    const int rr = tid >> 4;
    const int kr = tid & 15;

    float acc[4][4] = {};
    for (int k0 = 0; k0 < I; k0 += 64) {
#pragma unroll
        for (int i = 0; i < 4; ++i) {
            const int r = rr + 16 * i;
            const float4 av = *(const float4*)&A[(size_t)(m0 + r) * I + k0 + kr * 4];
            const float4 wv = *(const float4*)&W[(size_t)(n0 + r) * I + k0 + kr * 4];
            As[kr * 4 + 0][r] = av.x; As[kr * 4 + 1][r] = av.y;
            As[kr * 4 + 2][r] = av.z; As[kr * 4 + 3][r] = av.w;
            Ws[kr * 4 + 0][r] = wv.x; Ws[kr * 4 + 1][r] = wv.y;
            Ws[kr * 4 + 2][r] = wv.z; Ws[kr * 4 + 3][r] = wv.w;
        }
        __syncthreads();
#pragma unroll 8
        for (int kk = 0; kk < 64; ++kk) {
            const float4 a4 = *(const float4*)&As[kk][ty * 4];
            const float4 w4 = *(const float4*)&Ws[kk][tx * 4];
            const float a[4] = {a4.x, a4.y, a4.z, a4.w};
            const float w[4] = {w4.x, w4.y, w4.z, w4.w};
#pragma unroll
            for (int i = 0; i < 4; ++i)
#pragma unroll
                for (int jj = 0; jj < 4; ++jj)
                    acc[i][jj] = fmaf(a[i], w[jj], acc[i][jj]);
        }
        __syncthreads();
    }
    const int n = n0 + tx * 4;
    const float4 bi = *(const float4*)&bih[n];
    const float4 bh = *(const float4*)&bhh[n];
    const float4 bb = make_float4(bi.x + bh.x, bi.y + bh.y, bi.z + bh.z, bi.w + bh.w);
#pragma unroll
    for (int i = 0; i < 4; ++i) {
        const int m = m0 + ty * 4 + i;
        float4 o = make_float4(acc[i][0] + bb.x, acc[i][1] + bb.y,
                               acc[i][2] + bb.z, acc[i][3] + bb.w);
        *(float4*)&G[(size_t)m * G4 + n] = o;
    }
}

// ---------------- recurrent attention-LSTM: raw-barrier pipelined, NB=2 ----------------
// LDS: hid 131072 + sc 1024 + hH 1024 + hcI 2048 + hinI 1024 + red 8192 = 144384 B
__global__ __launch_bounds__(1024, 4) void alstm5(
    const int* __restrict__ lens,
    const float* __restrict__ G,       // [T*B][4H] fp32
    const half2_t* __restrict__ WhO,   // [1024][128] o-major
    const half2_t* __restrict__ WaO,   // [256][256]  j-major
    const float* __restrict__ ba,
    float* __restrict__ out)           // hs | h_fin | c_fin
{
    __shared__ __align__(16) half_t hid_s[NB][T][H];   // fp16 history
    __shared__ __align__(16) float  sc_s[NB][T];
    __shared__ __align__(16) half_t hH_s[NB][H];       // h (for scores)
    __shared__ __align__(16) half_t hcI_s[1024];       // [h|ctx], batch-interleaved k-pairs
    __shared__ __align__(16) half_t hinI_s[512];       // hin, batch-interleaved k-pairs
    __shared__ __align__(16) float  red_s[2048];       // phase-reuse reduce buffer

    const int b0 = blockIdx.x * NB;
    const int tid = threadIdx.x;
    const int lane = tid & 63;
    const int wave = tid >> 6;        // 0..15
    const int sb = wave >> 3;         // scores batch
    const int stp0 = wave & 7;        // scores t'-stride id
    const int cb = tid >> 9;          // ctx batch
    const int ck = (tid >> 8) & 1;    // ctx 2-way t-split
    const int cj = tid & 255;         // ctx feature
    const int ako = tid >> 8;         // Wa k-chunk 0..3
    const int aj = tid & 255;         // Wa output j
    const int eb = tid >> 8;          // cell batch (tid<512)
    const int ej = tid & 255;         // cell feature

    const int len0 = lens[b0], len1 = lens[b0 + 1];
    float c_reg = 0.f;
    float* hfin = out + (size_t)T * B * H;
    float* cfin = hfin + (size_t)B * H;
    if (tid < 512) hH_s[eb][ej] = (half_t)0.f;

    const uint4* wrow  = (const uint4*)(WhO + (size_t)tid * 128);                 // 32 x uint4
    const uint4* warow = (const uint4*)(WaO + (size_t)aj * 256 + (size_t)ako * 64); // 16 x uint4
    const uint4* hinv  = (const uint4*)hinI_s;
    const uint4* hcIv  = (const uint4*)hcI_s;

    BAR();

    for (int t = 0; t < T; ++t) {
        // ---- G-row prefetch into registers (consumed at cell update) ----
        float gpi = 0.f, gpf = 0.f, gpg = 0.f, gpo = 0.f;
        if (tid < 512) {
            const float* gb = G + ((size_t)t * B + b0 + eb) * G4 + ej;
            gpi = gb[0]; gpf = gb[H]; gpg = gb[2 * H]; gpo = gb[3 * H];
        }

        if (t > 0) {
            // ---- P0: Wa weight prefetch (8 deep) + scores ----
            uint4 wa_buf[8];
#pragma unroll
            for (int p = 0; p < 8; ++p) wa_buf[p] = warow[p];
            {
                const half2_t h2a = h2cast(*(const u32*)&hH_s[sb][lane * 4]);
                const half2_t h2b = h2cast(*(const u32*)&hH_s[sb][lane * 4 + 2]);
                for (int tp = stp0; tp < t; tp += 8) {
                    const uint2 hv = *(const uint2*)&hid_s[sb][tp][lane * 4];
                    float d = fdot2(h2cast(hv.x), h2a, fdot2(h2cast(hv.y), h2b, 0.f));
#pragma unroll
                    for (int off = 32; off; off >>= 1) d += __shfl_xor(d, off);
                    if (lane == 0) sc_s[sb][tp] = d;
                }
            }
            BAR();  // A
            // ---- P1: softmax (wave 0 -> batch 0, wave 8 -> batch 1) ----
            if (stp0 == 0) {
                const float v0 = (lane < t) ? sc_s[sb][lane] : -3.0e38f;
                const float v1 = (lane + 64 < t) ? sc_s[sb][lane + 64] : -3.0e38f;
                float m = fmaxf(v0, v1);
#pragma unroll
                for (int off = 32; off; off >>= 1) m = fmaxf(m, __shfl_xor(m, off));
                const float e0 = (lane < t) ? __expf(v0 - m) : 0.f;
                const float e1 = (lane + 64 < t) ? __expf(v1 - m) : 0.f;
                float s = e0 + e1;
#pragma unroll
                for (int off = 32; off; off >>= 1) s += __shfl_xor(s, off);
                const float inv = 1.f / s;
                if (lane < t) sc_s[sb][lane] = e0 * inv;
                if (lane + 64 < t) sc_s[sb][lane + 64] = e1 * inv;
            }
            BAR();  // B
            // ---- P2: ctx partials (2-way t-split per batch) ----
            {
                float cacc = 0.f;
                for (int tp = ck; tp < t; tp += 2)
                    cacc = fmaf(sc_s[cb][tp], (float)hid_s[cb][tp][cj], cacc);
                red_s[cb * 512 + ck * 256 + cj] = cacc;
            }
            BAR();  // C
            // ---- P3a: ctx reduce -> hcI ctx half ----
            if (tid < 512) {
                const float ctxv = red_s[eb * 512 + ej] + red_s[eb * 512 + 256 + ej];
                hcI_s[512 + 4 * (ej >> 1) + 2 * eb + (ej & 1)] = (half_t)ctxv;
            }
            BAR();  // D
            // ---- P3: Wa GEMV (pipelined uint4 weight stream) ----
            {
                float a0 = 0.f, a1 = 0.f;
#pragma unroll
                for (int gg = 0; gg < 16; ++gg) {
                    const uint4 w = wa_buf[gg & 7];
                    if (gg + 8 < 16) wa_buf[gg & 7] = warow[gg + 8];
                    const uint4 ha = hcIv[ako * 32 + 2 * gg];
                    const uint4 hb = hcIv[ako * 32 + 2 * gg + 1];
                    a0 = fdot2(h2cast(w.x), h2cast(ha.x), a0);
                    a1 = fdot2(h2cast(w.x), h2cast(ha.y), a1);
                    a0 = fdot2(h2cast(w.y), h2cast(ha.z), a0);
                    a1 = fdot2(h2cast(w.y), h2cast(ha.w), a1);
                    a0 = fdot2(h2cast(w.z), h2cast(hb.x), a0);
                    a1 = fdot2(h2cast(w.z), h2cast(hb.y), a1);
                    a0 = fdot2(h2cast(w.w), h2cast(hb.z), a0);
                    a1 = fdot2(h2cast(w.w), h2cast(hb.w), a1);
                }
                red_s[ako * 512 + aj] = a0;
                red_s[ako * 512 + 256 + aj] = a1;
            }
            BAR();  // E
            // ---- P4: Whh prefetch (8 deep) + hin reduce + tanh ----
            uint4 wh_buf[8];
#pragma unroll
            for (int p = 0; p < 8; ++p) wh_buf[p] = wrow[p];
            if (tid < 512) {
                float a = ba[ej];
#pragma unroll
                for (int r = 0; r < 4; ++r) a += red_s[r * 512 + eb * 256 + ej];
                hinI_s[4 * (ej >> 1) + 2 * eb + (ej & 1)] = (half_t)tanh_fast(a);
            }
            BAR();  // F
            // ---- P5: Whh GEMV (one output o=tid, both batches, pipelined) ----
            {
                float g0 = 0.f, g1 = 0.f;
#pragma unroll
                for (int gi = 0; gi < 32; ++gi) {
                    const uint4 w = wh_buf[gi & 7];
                    if (gi + 8 < 32) wh_buf[gi & 7] = wrow[gi + 8];
                    const uint4 ha = hinv[2 * gi];
                    const uint4 hb = hinv[2 * gi + 1];
                    g0 = fdot2(h2cast(w.x), h2cast(ha.x), g0);
                    g1 = fdot2(h2cast(w.x), h2cast(ha.y), g1);
                    g0 = fdot2(h2cast(w.y), h2cast(ha.z), g0);
                    g1 = fdot2(h2cast(w.y), h2cast(ha.w), g1);
                    g0 = fdot2(h2cast(w.z), h2cast(hb.x), g0);
                    g1 = fdot2(h2cast(w.z), h2cast(hb.y), g1);
                    g0 = fdot2(h2cast(w.w), h2cast(hb.z), g0);
                    g1 = fdot2(h2cast(w.w), h2cast(hb.w), g1);
                }
                red_s[tid] = g0;
                red_s[1024 + tid] = g1;
            }
        } else {
            // t == 0: h_in = 0 -> recurrent contribution is exactly 0; skip weight sweep
            red_s[tid] = 0.f;
            red_s[1024 + tid] = 0.f;
        }
        BAR();  // G
        // ---- P6: gate sum + cell update (threads 0..511) ----
        if (tid < 512) {
            const int bg = b0 + eb;
            const float gi_v = gpi + red_s[eb * 1024 + ej];
            const float gf_v = gpf + red_s[eb * 1024 + H + ej];
            const float gg_v = gpg + red_s[eb * 1024 + 2 * H + ej];
            const float go_v = gpo + red_s[eb * 1024 + 3 * H + ej];
            const float ig = sigmoid_fast(gi_v);
            const float fg = sigmoid_fast(gf_v);
            const float gv = tanh_fast(gg_v);
            const float og = sigmoid_fast(go_v);
            c_reg = fmaf(fg, c_reg, ig * gv);
            const float h_new = og * tanh_fast(c_reg);
            const half_t hh = (half_t)h_new;
            hH_s[eb][ej] = hh;
            hid_s[eb][t][ej] = hh;
            hcI_s[4 * (ej >> 1) + 2 * eb + (ej & 1)] = hh;
            out[((size_t)t * B + bg) * H + ej] = h_new;
            const int lb = eb ? len1 : len0;
            if (t == lb - 1) {
                hfin[(size_t)bg * H + ej] = h_new;
                cfin[(size_t)bg * H + ej] = c_reg;
            }
        }
        BAR();  // H
    }
}

extern "C" void kernel_launch(void* const* d_in, const int* in_sizes, int n_in,
                              void* d_out, int out_size, void* d_ws, size_t ws_size,
                              hipStream_t stream) {
    const float* embs = (const float*)d_in[0];
    const int*   lens = (const int*)d_in[1];
    const float* Wih  = (const float*)d_in[2];
    const float* Whh  = (const float*)d_in[3];
    const float* bih  = (const float*)d_in[4];
    const float* bhh  = (const float*)d_in[5];
    const float* Wa   = (const float*)d_in[6];
    const float* ba   = (const float*)d_in[7];
    float* out = (float*)d_out;

    // ws layout: G fp32 [T*B][4H] (64 MB) | WhO half2[1024*128] (512 KB) | WaO half2[256*256] (256 KB)
    float* G      = (float*)d_ws;
    half2_t* WhO  = (half2_t*)(G + (size_t)T * B * G4);
    half2_t* WaO  = WhO + (size_t)1024 * 128;

    pack_whO<<<G4, 128, 0, stream>>>(Whh, WhO);
    pack_waO<<<H, 256, 0, stream>>>(Wa, WaO);
    dim3 ggrid(T * B / 64, G4 / 64);
    gemm_g<<<ggrid, 256, 0, stream>>>(embs, Wih, bih, bhh, G);
    alstm5<<<B / NB, 1024, 0, stream>>>(lens, G, WhO, WaO, ba, out);
}